// Round 4
// baseline (521.328 us; speedup 1.0000x reference)
//
#include <hip/hip_runtime.h>

#define S_ 384
#define D_ 384
#define SD_ (384*384)

// output offsets (floats) in return order
#define OUT_EV 0
#define OUT_FS 56623104
#define OUT_IE 113246208
#define OUT_YM 113246209
#define OUT_FC 113246210
#define OUT_GI 113246594
#define OUT_CO 113246595
#define OUT_CH 113246979
#define OUT_TP 113246980

typedef __attribute__((ext_vector_type(4))) float f32x4;

__device__ __forceinline__ float waveSum(float v){
  v += __shfl_down(v,32); v += __shfl_down(v,16); v += __shfl_down(v,8);
  v += __shfl_down(v,4);  v += __shfl_down(v,2);  v += __shfl_down(v,1);
  return v;
}
__device__ __forceinline__ float waveMax(float v){
  v = fmaxf(v,__shfl_down(v,32)); v = fmaxf(v,__shfl_down(v,16)); v = fmaxf(v,__shfl_down(v,8));
  v = fmaxf(v,__shfl_down(v,4));  v = fmaxf(v,__shfl_down(v,2));  v = fmaxf(v,__shfl_down(v,1));
  return v;
}
__device__ __forceinline__ double waveSumD(double v){
  v += __shfl_down(v,32); v += __shfl_down(v,16); v += __shfl_down(v,8);
  v += __shfl_down(v,4);  v += __shfl_down(v,2);  v += __shfl_down(v,1);
  return v;
}

// ---- shared writer bodies (384 threads each) --------------------------------
// F[bs][i][j] = ga[bs,i] - gb[bs,j] + cm[i,j]; writer id -> (bs=id/6, 64-row chunk)
__device__ __forceinline__ void writeF_block(int id, int t,
    const float* __restrict__ ga, const float* __restrict__ gb,
    const float* __restrict__ cm, float* __restrict__ outF){
  __shared__ float gbs[D_];
  __shared__ float gas[64];
  int bs = id/6, ch = id%6, i0 = ch*64;
  gbs[t] = gb[bs*D_+t];
  if (t<64) gas[t] = ga[bs*D_+i0+t];
  __syncthreads();
  const f32x4* cm4 = (const f32x4*)(cm + i0*D_);
  const f32x4* gb4 = (const f32x4*)gbs;
  f32x4* o4 = (f32x4*)(outF + ((size_t)bs*S_ + i0)*D_);
  #pragma unroll
  for (int u=0; u<16; u++){
    int f = t + u*384;
    int il = f/96;
    int j4 = f - il*96;
    f32x4 o = gas[il] - gb4[j4] + cm4[f];
    __builtin_nontemporal_store(o, o4+f);
  }
}
// evolved[bs][i][d] = E[i][d] (replicated along first axis)
__device__ __forceinline__ void writeE_block(int id, int t,
    const float* __restrict__ E, float* __restrict__ outE){
  int bs = id/6, ch = id%6, i0 = ch*64;
  const f32x4* e4 = (const f32x4*)(E + i0*D_);
  f32x4* o4 = (f32x4*)(outE + ((size_t)bs*S_ + i0)*D_);
  #pragma unroll
  for (int u=0; u<16; u++){
    int f = t + u*384;
    __builtin_nontemporal_store(e4[f], o4+f);
  }
}

// ---- L1: prep (384 blocks) || cov_q (96) || cov_k (96). grid 576 x 384 -----
// cov recomputes the seq-gradient inline from q/k rows s±1 so it has no
// dependency on prep -> both fit in one launch.
__global__ __launch_bounds__(384) void k1(
    const float* __restrict__ q, const float* __restrict__ k,
    const float* __restrict__ W,
    float* __restrict__ ga, float* __restrict__ gb, float* __restrict__ cm,
    float* __restrict__ pq2,
    float* __restrict__ cq, float* __restrict__ ck, float* __restrict__ ckT){
  int b = blockIdx.x, t = threadIdx.x;
  if (b < 384){
    int s = b;
    float a = q[s*D_+t], bb = k[s*D_+t];
    float sq = waveSum(a), sk = waveSum(bb), sq2 = waveSum(a*a);
    __shared__ float red[3][6];
    int wid=t>>6, lane=t&63;
    if (lane==0){ red[0][wid]=sq; red[1][wid]=sk; red[2][wid]=sq2; }
    __syncthreads();
    float qm=0,km=0,q2=0;
    #pragma unroll
    for (int w=0;w<6;w++){ qm+=red[0][w]; km+=red[1][w]; q2+=red[2][w]; }
    qm *= (1.0f/D_); km *= (1.0f/D_);
    if (t==0) pq2[s]=q2;
    int sm=(s==0)?0:s-1, sp=(s==S_-1)?S_-1:s+1;
    float sc=(s==0||s==S_-1)?1.f:0.5f;
    ga[s*D_+t] = (q[sp*D_+t]-q[sm*D_+t])*sc;
    gb[s*D_+t] = (k[sp*D_+t]-k[sm*D_+t])*sc;
    cm[s*D_+t] = a*km - bb*qm;
  } else if (b < 480){
    // covq: 4 rows, wave-uniform row loads, coalesced W
    int s0 = (b-384)*4;
    const float* r0=q+(s0+0)*D_; const float* r1=q+(s0+1)*D_;
    const float* r2=q+(s0+2)*D_; const float* r3=q+(s0+3)*D_;
    float a0=0,a1=0,a2=0,a3=0;
    for (int e=0;e<D_;e+=4){
      float w0=W[(e+0)*D_+t], w1=W[(e+1)*D_+t], w2=W[(e+2)*D_+t], w3=W[(e+3)*D_+t];
      f32x4 x;
      x=*(const f32x4*)(r0+e); a0 += x.x*w0 + x.y*w1 + x.z*w2 + x.w*w3;
      x=*(const f32x4*)(r1+e); a1 += x.x*w0 + x.y*w1 + x.z*w2 + x.w*w3;
      x=*(const f32x4*)(r2+e); a2 += x.x*w0 + x.y*w1 + x.z*w2 + x.w*w3;
      x=*(const f32x4*)(r3+e); a3 += x.x*w0 + x.y*w1 + x.z*w2 + x.w*w3;
    }
    float acc[4]={a0,a1,a2,a3};
    #pragma unroll
    for (int r=0;r<4;r++){
      int s=s0+r;
      int sm=(s==0)?0:s-1, sp=(s==S_-1)?S_-1:s+1;
      float sc=(s==0||s==S_-1)?1.f:0.5f;
      cq[s*D_+t] = acc[r] + (q[sp*D_+t]-q[sm*D_+t])*sc;
    }
  } else {
    // covk: 4 rows + ckT transpose copy (f32x4 store)
    int s0 = (b-480)*4;
    const float* r0=k+(s0+0)*D_; const float* r1=k+(s0+1)*D_;
    const float* r2=k+(s0+2)*D_; const float* r3=k+(s0+3)*D_;
    float a0=0,a1=0,a2=0,a3=0;
    for (int e=0;e<D_;e+=4){
      float w0=W[(e+0)*D_+t], w1=W[(e+1)*D_+t], w2=W[(e+2)*D_+t], w3=W[(e+3)*D_+t];
      f32x4 x;
      x=*(const f32x4*)(r0+e); a0 += x.x*w0 + x.y*w1 + x.z*w2 + x.w*w3;
      x=*(const f32x4*)(r1+e); a1 += x.x*w0 + x.y*w1 + x.z*w2 + x.w*w3;
      x=*(const f32x4*)(r2+e); a2 += x.x*w0 + x.y*w1 + x.z*w2 + x.w*w3;
      x=*(const f32x4*)(r3+e); a3 += x.x*w0 + x.y*w1 + x.z*w2 + x.w*w3;
    }
    float acc[4]={a0,a1,a2,a3};
    float o[4];
    #pragma unroll
    for (int r=0;r<4;r++){
      int s=s0+r;
      int sm=(s==0)?0:s-1, sp=(s==S_-1)?S_-1:s+1;
      float sc=(s==0||s==S_-1)?1.f:0.5f;
      o[r] = acc[r] + (k[sp*D_+t]-k[sm*D_+t])*sc;
      ck[s*D_+t] = o[r];
    }
    f32x4 tr; tr.x=o[0]; tr.y=o[1]; tr.z=o[2]; tr.w=o[3];
    *(f32x4*)(ckT + t*D_ + s0) = tr;   // ckT[d][s]
  }
}

// ---- L2: attn (96) || mlp (96) || sums (384) || writeF all 2304. 2880 x 384
__global__ __launch_bounds__(384) void k2(
    const float* __restrict__ covq, const float* __restrict__ covk,
    const float* __restrict__ ckT, const float* __restrict__ v,
    const float* __restrict__ W1, const float* __restrict__ b1,
    const float* __restrict__ W2,
    float* __restrict__ E, float* __restrict__ pE2, float* __restrict__ pen,
    const float* __restrict__ ga, const float* __restrict__ gb,
    const float* __restrict__ cm,
    float* __restrict__ Sga, float* __restrict__ Sgb, float* __restrict__ Rcm,
    float* __restrict__ P2, float* __restrict__ Cga, float* __restrict__ Cgb,
    float* __restrict__ Ccm, float* __restrict__ outF){
  int b = blockIdx.x, t = threadIdx.x;
  if (b < 96){
    // attention: logits -> softmax -> E = A@V, E^2 partial
    int i0 = b*4;
    __shared__ float P[4][D_];
    __shared__ float wred[4][6];
    __shared__ float wred2[4][6];
    __shared__ float sred[6];
    const float* q0=covq+(i0+0)*D_; const float* q1=covq+(i0+1)*D_;
    const float* q2=covq+(i0+2)*D_; const float* q3=covq+(i0+3)*D_;
    float l0=0,l1=0,l2=0,l3=0;
    for (int e=0;e<D_;e+=4){
      float c0=ckT[(e+0)*D_+t], c1=ckT[(e+1)*D_+t], c2=ckT[(e+2)*D_+t], c3=ckT[(e+3)*D_+t];
      f32x4 a;
      a=*(const f32x4*)(q0+e); l0 += a.x*c0 + a.y*c1 + a.z*c2 + a.w*c3;
      a=*(const f32x4*)(q1+e); l1 += a.x*c0 + a.y*c1 + a.z*c2 + a.w*c3;
      a=*(const f32x4*)(q2+e); l2 += a.x*c0 + a.y*c1 + a.z*c2 + a.w*c3;
      a=*(const f32x4*)(q3+e); l3 += a.x*c0 + a.y*c1 + a.z*c2 + a.w*c3;
    }
    const float isq = 0.05103103630798288f; // 1/sqrt(384)
    l0*=isq; l1*=isq; l2*=isq; l3*=isq;
    float m0=waveMax(l0), m1=waveMax(l1), m2=waveMax(l2), m3=waveMax(l3);
    int wid=t>>6, lane=t&63;
    if (lane==0){ wred[0][wid]=m0; wred[1][wid]=m1; wred[2][wid]=m2; wred[3][wid]=m3; }
    __syncthreads();
    float mx0=wred[0][0], mx1=wred[1][0], mx2=wred[2][0], mx3=wred[3][0];
    for (int w=1; w<6; w++){
      mx0=fmaxf(mx0,wred[0][w]); mx1=fmaxf(mx1,wred[1][w]);
      mx2=fmaxf(mx2,wred[2][w]); mx3=fmaxf(mx3,wred[3][w]);
    }
    float e0=expf(l0-mx0), e1=expf(l1-mx1), e2=expf(l2-mx2), e3=expf(l3-mx3);
    float s0=waveSum(e0), s1=waveSum(e1), s2=waveSum(e2), s3=waveSum(e3);
    if (lane==0){ wred2[0][wid]=s0; wred2[1][wid]=s1; wred2[2][wid]=s2; wred2[3][wid]=s3; }
    __syncthreads();
    float d0=0,d1=0,d2=0,d3=0;
    for (int w=0; w<6; w++){ d0+=wred2[0][w]; d1+=wred2[1][w]; d2+=wred2[2][w]; d3+=wred2[3][w]; }
    P[0][t]=e0/d0; P[1][t]=e1/d1; P[2][t]=e2/d2; P[3][t]=e3/d3;
    __syncthreads();
    float ea0=0,ea1=0,ea2=0,ea3=0;
    for (int t2=0; t2<D_; t2+=4){
      float v0 = v[(t2+0)*D_+t];
      float v1 = v[(t2+1)*D_+t];
      float v2 = v[(t2+2)*D_+t];
      float v3 = v[(t2+3)*D_+t];
      f32x4 p;
      p=*(const f32x4*)&P[0][t2]; ea0 += p.x*v0 + p.y*v1 + p.z*v2 + p.w*v3;
      p=*(const f32x4*)&P[1][t2]; ea1 += p.x*v0 + p.y*v1 + p.z*v2 + p.w*v3;
      p=*(const f32x4*)&P[2][t2]; ea2 += p.x*v0 + p.y*v1 + p.z*v2 + p.w*v3;
      p=*(const f32x4*)&P[3][t2]; ea3 += p.x*v0 + p.y*v1 + p.z*v2 + p.w*v3;
    }
    E[(i0+0)*D_+t]=ea0; E[(i0+1)*D_+t]=ea1; E[(i0+2)*D_+t]=ea2; E[(i0+3)*D_+t]=ea3;
    float se2 = ea0*ea0+ea1*ea1+ea2*ea2+ea3*ea3;
    se2 = waveSum(se2);
    if (lane==0) sred[wid]=se2;
    __syncthreads();
    if (t==0) pE2[b] = sred[0]+sred[1]+sred[2]+sred[3]+sred[4]+sred[5];
  } else if (b < 192){
    // interaction-energy MLP partials (needs only covq/covk from L1)
    int s0 = (b-96)*4;
    __shared__ float sred2[6];
    const float* c0=covq+(s0+0)*D_; const float* c1=covq+(s0+1)*D_;
    const float* c2=covq+(s0+2)*D_; const float* c3=covq+(s0+3)*D_;
    const float* d0=covk+(s0+0)*D_; const float* d1=covk+(s0+1)*D_;
    const float* d2=covk+(s0+2)*D_; const float* d3=covk+(s0+3)*D_;
    float h0=0,h1=0,h2=0,h3=0;
    for (int e=0; e<D_; e+=4){
      float w0=W1[(e+0)*D_+t], w1=W1[(e+1)*D_+t], w2=W1[(e+2)*D_+t], w3=W1[(e+3)*D_+t];
      f32x4 x;
      x=*(const f32x4*)(c0+e); h0 += x.x*w0 + x.y*w1 + x.z*w2 + x.w*w3;
      x=*(const f32x4*)(c1+e); h1 += x.x*w0 + x.y*w1 + x.z*w2 + x.w*w3;
      x=*(const f32x4*)(c2+e); h2 += x.x*w0 + x.y*w1 + x.z*w2 + x.w*w3;
      x=*(const f32x4*)(c3+e); h3 += x.x*w0 + x.y*w1 + x.z*w2 + x.w*w3;
    }
    for (int e=0; e<D_; e+=4){
      float w0=W1[(D_+e+0)*D_+t], w1=W1[(D_+e+1)*D_+t], w2=W1[(D_+e+2)*D_+t], w3=W1[(D_+e+3)*D_+t];
      f32x4 x;
      x=*(const f32x4*)(d0+e); h0 += x.x*w0 + x.y*w1 + x.z*w2 + x.w*w3;
      x=*(const f32x4*)(d1+e); h1 += x.x*w0 + x.y*w1 + x.z*w2 + x.w*w3;
      x=*(const f32x4*)(d2+e); h2 += x.x*w0 + x.y*w1 + x.z*w2 + x.w*w3;
      x=*(const f32x4*)(d3+e); h3 += x.x*w0 + x.y*w1 + x.z*w2 + x.w*w3;
    }
    float bb=b1[t], w2c=W2[t];
    h0=fmaxf(h0+bb,0.f); h1=fmaxf(h1+bb,0.f); h2=fmaxf(h2+bb,0.f); h3=fmaxf(h3+bb,0.f);
    float p = (h0+h1+h2+h3)*w2c;
    p = waveSum(p);
    int wid=t>>6, lane=t&63;
    if (lane==0) sred2[wid]=p;
    __syncthreads();
    if (t==0) pen[b-96] = sred2[0]+sred2[1]+sred2[2]+sred2[3]+sred2[4]+sred2[5];
  } else if (b < 576){
    // row/col sums of ga, gb, cm for the algebraic F-reduction
    int rb = b-192;
    float ra=ga[rb*D_+t], rg=gb[rb*D_+t], rc=cm[rb*D_+t];   // row rb (coalesced)
    float ca=ga[t*D_+rb], cg=gb[t*D_+rb], cc=cm[t*D_+rb];   // col rb
    float p2 = ra*ra + rg*rg + rc*rc;
    float s0=waveSum(ra), s1=waveSum(rg), s2=waveSum(rc), s3=waveSum(p2);
    float s4=waveSum(ca), s5=waveSum(cg), s6=waveSum(cc);
    __shared__ float red[7][6];
    int wid=t>>6, lane=t&63;
    if (lane==0){ red[0][wid]=s0; red[1][wid]=s1; red[2][wid]=s2; red[3][wid]=s3;
                  red[4][wid]=s4; red[5][wid]=s5; red[6][wid]=s6; }
    __syncthreads();
    if (t==0){
      float a0=0,a1=0,a2=0,a3=0,a4=0,a5=0,a6=0;
      for (int w=0;w<6;w++){ a0+=red[0][w]; a1+=red[1][w]; a2+=red[2][w]; a3+=red[3][w];
                             a4+=red[4][w]; a5+=red[5][w]; a6+=red[6][w]; }
      Sga[rb]=a0; Sgb[rb]=a1; Rcm[rb]=a2; P2[rb]=a3; Cga[rb]=a4; Cgb[rb]=a5; Ccm[rb]=a6;
    }
  } else {
    writeF_block(b-576, t, ga, gb, cm, outF);
  }
}

// ---- L3: fin (block 0) || writeE all 2304. grid 2305 x 384 -----------------
__global__ __launch_bounds__(384) void k3(
    const float* __restrict__ E, float* __restrict__ outE,
    const float* __restrict__ pq2,
    const float* __restrict__ Sga, const float* __restrict__ Sgb,
    const float* __restrict__ Rcm, const float* __restrict__ P2,
    const float* __restrict__ Cga, const float* __restrict__ Cgb,
    const float* __restrict__ Ccm,
    const float* __restrict__ pE2, const float* __restrict__ pen,
    const float* __restrict__ coup, const float* __restrict__ b2,
    float* __restrict__ out){
  int b = blockIdx.x, t = threadIdx.x;
  if (b == 0){
    double v[10];
    v[0]=pq2[t];
    v[1]=Sga[t]; v[2]=Sgb[t]; v[3]=Rcm[t]; v[4]=P2[t];
    v[5]=(double)Sga[t]*Sgb[t];
    v[6]=(double)Cga[t]*Rcm[t];
    v[7]=(double)Cgb[t]*Ccm[t];
    v[8]=(t<96)? (double)pE2[t] : 0.0;
    v[9]=(t<96)? (double)pen[t] : 0.0;
    __shared__ double red[10][6];
    int wid=t>>6, lane=t&63;
    #pragma unroll
    for (int i=0;i<10;i++){
      double s = waveSumD(v[i]);
      if (lane==0) red[i][wid]=s;
    }
    __syncthreads();
    double tot[10];
    #pragma unroll
    for (int i=0;i<10;i++){
      double s=0; for (int w=0;w<6;w++) s+=red[i][w];
      tot[i]=s;
    }
    double init_e=tot[0], fin_e=tot[8], en=tot[9];
    double sumF  = 384.0*(tot[1]-tot[2]+tot[3]);
    double sumF2 = 384.0*tot[4] - 2.0*tot[5] + 2.0*tot[6] - 2.0*tot[7];
    float cons = (float)(fabs(fin_e - init_e)/(init_e + 1e-8));
    out[OUT_FC + t] = 0.0f;    // evolved constant along s -> second gradient == 0
    out[OUT_CO + t] = cons;
    if (t == 0){
      out[OUT_IE] = (float)en + 384.0f*b2[0];
      out[OUT_YM] = coup[0]*(float)sumF2;
      out[OUT_GI] = 1.0f;      // softmax row sums == 1 -> std ~ 0 -> clip = 1
      out[OUT_CH] = 1.0f;      // corrcoef of single row
      out[OUT_TP] = (float)(sumF/(6.283185307179586*384.0));
    }
  } else {
    writeE_block(b-1, t, E, outE);
  }
}

extern "C" void kernel_launch(void* const* d_in, const int* in_sizes, int n_in,
                              void* d_out, int out_size, void* d_ws, size_t ws_size,
                              hipStream_t stream) {
  const float* q    = (const float*)d_in[0];
  const float* k    = (const float*)d_in[1];
  const float* v    = (const float*)d_in[2];
  // d_in[3] gauge_weights: cancels in softmax, unused
  const float* Wcov = (const float*)d_in[4];
  const float* coup = (const float*)d_in[5];
  const float* W1   = (const float*)d_in[6];
  const float* b1   = (const float*)d_in[7];
  const float* W2   = (const float*)d_in[8];
  const float* b2   = (const float*)d_in[9];
  float* out = (float*)d_out;
  float* ws  = (float*)d_ws;
  float* ga   = ws;
  float* gb   = ws + 1*SD_;
  float* cm   = ws + 2*SD_;
  float* cq   = ws + 3*SD_;
  float* ck   = ws + 4*SD_;
  float* ckT  = ws + 5*SD_;
  float* E    = ws + 6*SD_;
  float* base = ws + 7*SD_;
  float* pq2 = base;        // 384
  float* Sga = base + 384;  float* Sgb = base + 768;
  float* Rcm = base + 1152; float* P2  = base + 1536;
  float* Cga = base + 1920; float* Cgb = base + 2304;
  float* Ccm = base + 2688;
  float* pE2 = base + 3072; // 96
  float* pen = base + 3168; // 96

  k1<<<dim3(576),  dim3(384), 0, stream>>>(q, k, Wcov, ga, gb, cm, pq2, cq, ck, ckT);
  k2<<<dim3(2880), dim3(384), 0, stream>>>(cq, ck, ckT, v, W1, b1, W2, E, pE2, pen,
                                           ga, gb, cm, Sga, Sgb, Rcm, P2, Cga, Cgb, Ccm,
                                           out + OUT_FS);
  k3<<<dim3(2305), dim3(384), 0, stream>>>(E, out + OUT_EV,
                                           pq2, Sga, Sgb, Rcm, P2, Cga, Cgb, Ccm,
                                           pE2, pen, coup, b2, out);
}

// Round 8
// 516.077 us; speedup vs baseline: 1.0102x; 1.0102x over previous
//
#include <hip/hip_runtime.h>

#define S_ 384
#define D_ 384
#define SD_ (384*384)

// output offsets (floats) in return order
#define OUT_EV 0
#define OUT_FS 56623104
#define OUT_IE 113246208
#define OUT_YM 113246209
#define OUT_FC 113246210
#define OUT_GI 113246594
#define OUT_CO 113246595
#define OUT_CH 113246979
#define OUT_TP 113246980

typedef __attribute__((ext_vector_type(4))) float f32x4;

__device__ __forceinline__ float waveSum(float v){
  v += __shfl_down(v,32); v += __shfl_down(v,16); v += __shfl_down(v,8);
  v += __shfl_down(v,4);  v += __shfl_down(v,2);  v += __shfl_down(v,1);
  return v;
}
__device__ __forceinline__ float waveMax(float v){
  v = fmaxf(v,__shfl_down(v,32)); v = fmaxf(v,__shfl_down(v,16)); v = fmaxf(v,__shfl_down(v,8));
  v = fmaxf(v,__shfl_down(v,4));  v = fmaxf(v,__shfl_down(v,2));  v = fmaxf(v,__shfl_down(v,1));
  return v;
}
__device__ __forceinline__ double waveSumD(double v){
  v += __shfl_down(v,32); v += __shfl_down(v,16); v += __shfl_down(v,8);
  v += __shfl_down(v,4);  v += __shfl_down(v,2);  v += __shfl_down(v,1);
  return v;
}

// ---- shared writer bodies (384 threads each) --------------------------------
// F[bs][i][j] = ga[bs,i] - gb[bs,j] + cm[i,j]; writer id -> (bs=id/6, 64-row chunk)
// PLAIN stores (NT removed): in-run fillBuffer proves plain stores hit 6.3 TB/s;
// nt bypasses L2 write-combining and measured ~1 TB/s effective.
__device__ __forceinline__ void writeF_block(int id, int t,
    const float* __restrict__ ga, const float* __restrict__ gb,
    const float* __restrict__ cm, float* __restrict__ outF){
  __shared__ float gbs[D_];
  __shared__ float gas[64];
  int bs = id/6, ch = id%6, i0 = ch*64;
  gbs[t] = gb[bs*D_+t];
  if (t<64) gas[t] = ga[bs*D_+i0+t];
  __syncthreads();
  const f32x4* cm4 = (const f32x4*)(cm + i0*D_);
  const f32x4* gb4 = (const f32x4*)gbs;
  f32x4* o4 = (f32x4*)(outF + ((size_t)bs*S_ + i0)*D_);
  #pragma unroll
  for (int u=0; u<16; u++){
    int f = t + u*384;
    int il = f/96;
    int j4 = f - il*96;
    f32x4 o = gas[il] - gb4[j4] + cm4[f];
    o4[f] = o;
  }
}
// evolved[bs][i][d] = E[i][d] (replicated along first axis)
__device__ __forceinline__ void writeE_block(int id, int t,
    const float* __restrict__ E, float* __restrict__ outE){
  int bs = id/6, ch = id%6, i0 = ch*64;
  const f32x4* e4 = (const f32x4*)(E + i0*D_);
  f32x4* o4 = (f32x4*)(outE + ((size_t)bs*S_ + i0)*D_);
  #pragma unroll
  for (int u=0; u<16; u++){
    int f = t + u*384;
    o4[f] = e4[f];
  }
}

// ---- L1: prep (384 blocks) || cov_q (96) || cov_k (96). grid 576 x 384 -----
// cov recomputes the seq-gradient inline from q/k rows s±1 so it has no
// dependency on prep -> both fit in one launch.
__global__ __launch_bounds__(384) void k1(
    const float* __restrict__ q, const float* __restrict__ k,
    const float* __restrict__ W,
    float* __restrict__ ga, float* __restrict__ gb, float* __restrict__ cm,
    float* __restrict__ pq2,
    float* __restrict__ cq, float* __restrict__ ck, float* __restrict__ ckT){
  int b = blockIdx.x, t = threadIdx.x;
  if (b < 384){
    int s = b;
    float a = q[s*D_+t], bb = k[s*D_+t];
    float sq = waveSum(a), sk = waveSum(bb), sq2 = waveSum(a*a);
    __shared__ float red[3][6];
    int wid=t>>6, lane=t&63;
    if (lane==0){ red[0][wid]=sq; red[1][wid]=sk; red[2][wid]=sq2; }
    __syncthreads();
    float qm=0,km=0,q2=0;
    #pragma unroll
    for (int w=0;w<6;w++){ qm+=red[0][w]; km+=red[1][w]; q2+=red[2][w]; }
    qm *= (1.0f/D_); km *= (1.0f/D_);
    if (t==0) pq2[s]=q2;
    int sm=(s==0)?0:s-1, sp=(s==S_-1)?S_-1:s+1;
    float sc=(s==0||s==S_-1)?1.f:0.5f;
    ga[s*D_+t] = (q[sp*D_+t]-q[sm*D_+t])*sc;
    gb[s*D_+t] = (k[sp*D_+t]-k[sm*D_+t])*sc;
    cm[s*D_+t] = a*km - bb*qm;
  } else if (b < 480){
    // covq: 4 rows, wave-uniform row loads, coalesced W
    int s0 = (b-384)*4;
    const float* r0=q+(s0+0)*D_; const float* r1=q+(s0+1)*D_;
    const float* r2=q+(s0+2)*D_; const float* r3=q+(s0+3)*D_;
    float a0=0,a1=0,a2=0,a3=0;
    for (int e=0;e<D_;e+=4){
      float w0=W[(e+0)*D_+t], w1=W[(e+1)*D_+t], w2=W[(e+2)*D_+t], w3=W[(e+3)*D_+t];
      f32x4 x;
      x=*(const f32x4*)(r0+e); a0 += x.x*w0 + x.y*w1 + x.z*w2 + x.w*w3;
      x=*(const f32x4*)(r1+e); a1 += x.x*w0 + x.y*w1 + x.z*w2 + x.w*w3;
      x=*(const f32x4*)(r2+e); a2 += x.x*w0 + x.y*w1 + x.z*w2 + x.w*w3;
      x=*(const f32x4*)(r3+e); a3 += x.x*w0 + x.y*w1 + x.z*w2 + x.w*w3;
    }
    float acc[4]={a0,a1,a2,a3};
    #pragma unroll
    for (int r=0;r<4;r++){
      int s=s0+r;
      int sm=(s==0)?0:s-1, sp=(s==S_-1)?S_-1:s+1;
      float sc=(s==0||s==S_-1)?1.f:0.5f;
      cq[s*D_+t] = acc[r] + (q[sp*D_+t]-q[sm*D_+t])*sc;
    }
  } else {
    // covk: 4 rows + ckT transpose copy (f32x4 store)
    int s0 = (b-480)*4;
    const float* r0=k+(s0+0)*D_; const float* r1=k+(s0+1)*D_;
    const float* r2=k+(s0+2)*D_; const float* r3=k+(s0+3)*D_;
    float a0=0,a1=0,a2=0,a3=0;
    for (int e=0;e<D_;e+=4){
      float w0=W[(e+0)*D_+t], w1=W[(e+1)*D_+t], w2=W[(e+2)*D_+t], w3=W[(e+3)*D_+t];
      f32x4 x;
      x=*(const f32x4*)(r0+e); a0 += x.x*w0 + x.y*w1 + x.z*w2 + x.w*w3;
      x=*(const f32x4*)(r1+e); a1 += x.x*w0 + x.y*w1 + x.z*w2 + x.w*w3;
      x=*(const f32x4*)(r2+e); a2 += x.x*w0 + x.y*w1 + x.z*w2 + x.w*w3;
      x=*(const f32x4*)(r3+e); a3 += x.x*w0 + x.y*w1 + x.z*w2 + x.w*w3;
    }
    float acc[4]={a0,a1,a2,a3};
    float o[4];
    #pragma unroll
    for (int r=0;r<4;r++){
      int s=s0+r;
      int sm=(s==0)?0:s-1, sp=(s==S_-1)?S_-1:s+1;
      float sc=(s==0||s==S_-1)?1.f:0.5f;
      o[r] = acc[r] + (k[sp*D_+t]-k[sm*D_+t])*sc;
      ck[s*D_+t] = o[r];
    }
    f32x4 tr; tr.x=o[0]; tr.y=o[1]; tr.z=o[2]; tr.w=o[3];
    *(f32x4*)(ckT + t*D_ + s0) = tr;   // ckT[d][s]
  }
}

// ---- L2: attn (96) || mlp (96) || sums (384) || writeF all 2304. 2880 x 384
__global__ __launch_bounds__(384) void k2(
    const float* __restrict__ covq, const float* __restrict__ covk,
    const float* __restrict__ ckT, const float* __restrict__ v,
    const float* __restrict__ W1, const float* __restrict__ b1,
    const float* __restrict__ W2,
    float* __restrict__ E, float* __restrict__ pE2, float* __restrict__ pen,
    const float* __restrict__ ga, const float* __restrict__ gb,
    const float* __restrict__ cm,
    float* __restrict__ Sga, float* __restrict__ Sgb, float* __restrict__ Rcm,
    float* __restrict__ P2, float* __restrict__ Cga, float* __restrict__ Cgb,
    float* __restrict__ Ccm, float* __restrict__ outF){
  int b = blockIdx.x, t = threadIdx.x;
  if (b < 96){
    // attention: logits -> softmax -> E = A@V, E^2 partial
    int i0 = b*4;
    __shared__ float P[4][D_];
    __shared__ float wred[4][6];
    __shared__ float wred2[4][6];
    __shared__ float sred[6];
    const float* q0=covq+(i0+0)*D_; const float* q1=covq+(i0+1)*D_;
    const float* q2=covq+(i0+2)*D_; const float* q3=covq+(i0+3)*D_;
    float l0=0,l1=0,l2=0,l3=0;
    for (int e=0;e<D_;e+=4){
      float c0=ckT[(e+0)*D_+t], c1=ckT[(e+1)*D_+t], c2=ckT[(e+2)*D_+t], c3=ckT[(e+3)*D_+t];
      f32x4 a;
      a=*(const f32x4*)(q0+e); l0 += a.x*c0 + a.y*c1 + a.z*c2 + a.w*c3;
      a=*(const f32x4*)(q1+e); l1 += a.x*c0 + a.y*c1 + a.z*c2 + a.w*c3;
      a=*(const f32x4*)(q2+e); l2 += a.x*c0 + a.y*c1 + a.z*c2 + a.w*c3;
      a=*(const f32x4*)(q3+e); l3 += a.x*c0 + a.y*c1 + a.z*c2 + a.w*c3;
    }
    const float isq = 0.05103103630798288f; // 1/sqrt(384)
    l0*=isq; l1*=isq; l2*=isq; l3*=isq;
    float m0=waveMax(l0), m1=waveMax(l1), m2=waveMax(l2), m3=waveMax(l3);
    int wid=t>>6, lane=t&63;
    if (lane==0){ wred[0][wid]=m0; wred[1][wid]=m1; wred[2][wid]=m2; wred[3][wid]=m3; }
    __syncthreads();
    float mx0=wred[0][0], mx1=wred[1][0], mx2=wred[2][0], mx3=wred[3][0];
    for (int w=1; w<6; w++){
      mx0=fmaxf(mx0,wred[0][w]); mx1=fmaxf(mx1,wred[1][w]);
      mx2=fmaxf(mx2,wred[2][w]); mx3=fmaxf(mx3,wred[3][w]);
    }
    float e0=expf(l0-mx0), e1=expf(l1-mx1), e2=expf(l2-mx2), e3=expf(l3-mx3);
    float s0=waveSum(e0), s1=waveSum(e1), s2=waveSum(e2), s3=waveSum(e3);
    if (lane==0){ wred2[0][wid]=s0; wred2[1][wid]=s1; wred2[2][wid]=s2; wred2[3][wid]=s3; }
    __syncthreads();
    float d0=0,d1=0,d2=0,d3=0;
    for (int w=0; w<6; w++){ d0+=wred2[0][w]; d1+=wred2[1][w]; d2+=wred2[2][w]; d3+=wred2[3][w]; }
    P[0][t]=e0/d0; P[1][t]=e1/d1; P[2][t]=e2/d2; P[3][t]=e3/d3;
    __syncthreads();
    float ea0=0,ea1=0,ea2=0,ea3=0;
    for (int t2=0; t2<D_; t2+=4){
      float v0 = v[(t2+0)*D_+t];
      float v1 = v[(t2+1)*D_+t];
      float v2 = v[(t2+2)*D_+t];
      float v3 = v[(t2+3)*D_+t];
      f32x4 p;
      p=*(const f32x4*)&P[0][t2]; ea0 += p.x*v0 + p.y*v1 + p.z*v2 + p.w*v3;
      p=*(const f32x4*)&P[1][t2]; ea1 += p.x*v0 + p.y*v1 + p.z*v2 + p.w*v3;
      p=*(const f32x4*)&P[2][t2]; ea2 += p.x*v0 + p.y*v1 + p.z*v2 + p.w*v3;
      p=*(const f32x4*)&P[3][t2]; ea3 += p.x*v0 + p.y*v1 + p.z*v2 + p.w*v3;
    }
    E[(i0+0)*D_+t]=ea0; E[(i0+1)*D_+t]=ea1; E[(i0+2)*D_+t]=ea2; E[(i0+3)*D_+t]=ea3;
    float se2 = ea0*ea0+ea1*ea1+ea2*ea2+ea3*ea3;
    se2 = waveSum(se2);
    if (lane==0) sred[wid]=se2;
    __syncthreads();
    if (t==0) pE2[b] = sred[0]+sred[1]+sred[2]+sred[3]+sred[4]+sred[5];
  } else if (b < 192){
    // interaction-energy MLP partials (needs only covq/covk from L1)
    int s0 = (b-96)*4;
    __shared__ float sred2[6];
    const float* c0=covq+(s0+0)*D_; const float* c1=covq+(s0+1)*D_;
    const float* c2=covq+(s0+2)*D_; const float* c3=covq+(s0+3)*D_;
    const float* d0=covk+(s0+0)*D_; const float* d1=covk+(s0+1)*D_;
    const float* d2=covk+(s0+2)*D_; const float* d3=covk+(s0+3)*D_;
    float h0=0,h1=0,h2=0,h3=0;
    for (int e=0; e<D_; e+=4){
      float w0=W1[(e+0)*D_+t], w1=W1[(e+1)*D_+t], w2=W1[(e+2)*D_+t], w3=W1[(e+3)*D_+t];
      f32x4 x;
      x=*(const f32x4*)(c0+e); h0 += x.x*w0 + x.y*w1 + x.z*w2 + x.w*w3;
      x=*(const f32x4*)(c1+e); h1 += x.x*w0 + x.y*w1 + x.z*w2 + x.w*w3;
      x=*(const f32x4*)(c2+e); h2 += x.x*w0 + x.y*w1 + x.z*w2 + x.w*w3;
      x=*(const f32x4*)(c3+e); h3 += x.x*w0 + x.y*w1 + x.z*w2 + x.w*w3;
    }
    for (int e=0; e<D_; e+=4){
      float w0=W1[(D_+e+0)*D_+t], w1=W1[(D_+e+1)*D_+t], w2=W1[(D_+e+2)*D_+t], w3=W1[(D_+e+3)*D_+t];
      f32x4 x;
      x=*(const f32x4*)(d0+e); h0 += x.x*w0 + x.y*w1 + x.z*w2 + x.w*w3;
      x=*(const f32x4*)(d1+e); h1 += x.x*w0 + x.y*w1 + x.z*w2 + x.w*w3;
      x=*(const f32x4*)(d2+e); h2 += x.x*w0 + x.y*w1 + x.z*w2 + x.w*w3;
      x=*(const f32x4*)(d3+e); h3 += x.x*w0 + x.y*w1 + x.z*w2 + x.w*w3;
    }
    float bb=b1[t], w2c=W2[t];
    h0=fmaxf(h0+bb,0.f); h1=fmaxf(h1+bb,0.f); h2=fmaxf(h2+bb,0.f); h3=fmaxf(h3+bb,0.f);
    float p = (h0+h1+h2+h3)*w2c;
    p = waveSum(p);
    int wid=t>>6, lane=t&63;
    if (lane==0) sred2[wid]=p;
    __syncthreads();
    if (t==0) pen[b-96] = sred2[0]+sred2[1]+sred2[2]+sred2[3]+sred2[4]+sred2[5];
  } else if (b < 576){
    // row/col sums of ga, gb, cm for the algebraic F-reduction
    int rb = b-192;
    float ra=ga[rb*D_+t], rg=gb[rb*D_+t], rc=cm[rb*D_+t];   // row rb (coalesced)
    float ca=ga[t*D_+rb], cg=gb[t*D_+rb], cc=cm[t*D_+rb];   // col rb
    float p2 = ra*ra + rg*rg + rc*rc;
    float s0=waveSum(ra), s1=waveSum(rg), s2=waveSum(rc), s3=waveSum(p2);
    float s4=waveSum(ca), s5=waveSum(cg), s6=waveSum(cc);
    __shared__ float red[7][6];
    int wid=t>>6, lane=t&63;
    if (lane==0){ red[0][wid]=s0; red[1][wid]=s1; red[2][wid]=s2; red[3][wid]=s3;
                  red[4][wid]=s4; red[5][wid]=s5; red[6][wid]=s6; }
    __syncthreads();
    if (t==0){
      float a0=0,a1=0,a2=0,a3=0,a4=0,a5=0,a6=0;
      for (int w=0;w<6;w++){ a0+=red[0][w]; a1+=red[1][w]; a2+=red[2][w]; a3+=red[3][w];
                             a4+=red[4][w]; a5+=red[5][w]; a6+=red[6][w]; }
      Sga[rb]=a0; Sgb[rb]=a1; Rcm[rb]=a2; P2[rb]=a3; Cga[rb]=a4; Cgb[rb]=a5; Ccm[rb]=a6;
    }
  } else {
    writeF_block(b-576, t, ga, gb, cm, outF);
  }
}

// ---- L3: fin (block 0) || writeE all 2304. grid 2305 x 384 -----------------
__global__ __launch_bounds__(384) void k3(
    const float* __restrict__ E, float* __restrict__ outE,
    const float* __restrict__ pq2,
    const float* __restrict__ Sga, const float* __restrict__ Sgb,
    const float* __restrict__ Rcm, const float* __restrict__ P2,
    const float* __restrict__ Cga, const float* __restrict__ Cgb,
    const float* __restrict__ Ccm,
    const float* __restrict__ pE2, const float* __restrict__ pen,
    const float* __restrict__ coup, const float* __restrict__ b2,
    float* __restrict__ out){
  int b = blockIdx.x, t = threadIdx.x;
  if (b == 0){
    double v[10];
    v[0]=pq2[t];
    v[1]=Sga[t]; v[2]=Sgb[t]; v[3]=Rcm[t]; v[4]=P2[t];
    v[5]=(double)Sga[t]*Sgb[t];
    v[6]=(double)Cga[t]*Rcm[t];
    v[7]=(double)Cgb[t]*Ccm[t];
    v[8]=(t<96)? (double)pE2[t] : 0.0;
    v[9]=(t<96)? (double)pen[t] : 0.0;
    __shared__ double red[10][6];
    int wid=t>>6, lane=t&63;
    #pragma unroll
    for (int i=0;i<10;i++){
      double s = waveSumD(v[i]);
      if (lane==0) red[i][wid]=s;
    }
    __syncthreads();
    double tot[10];
    #pragma unroll
    for (int i=0;i<10;i++){
      double s=0; for (int w=0;w<6;w++) s+=red[i][w];
      tot[i]=s;
    }
    double init_e=tot[0], fin_e=tot[8], en=tot[9];
    double sumF  = 384.0*(tot[1]-tot[2]+tot[3]);
    double sumF2 = 384.0*tot[4] - 2.0*tot[5] + 2.0*tot[6] - 2.0*tot[7];
    float cons = (float)(fabs(fin_e - init_e)/(init_e + 1e-8));
    out[OUT_FC + t] = 0.0f;    // evolved constant along s -> second gradient == 0
    out[OUT_CO + t] = cons;
    if (t == 0){
      out[OUT_IE] = (float)en + 384.0f*b2[0];
      out[OUT_YM] = coup[0]*(float)sumF2;
      out[OUT_GI] = 1.0f;      // softmax row sums == 1 -> std ~ 0 -> clip = 1
      out[OUT_CH] = 1.0f;      // corrcoef of single row
      out[OUT_TP] = (float)(sumF/(6.283185307179586*384.0));
    }
  } else {
    writeE_block(b-1, t, E, outE);
  }
}

extern "C" void kernel_launch(void* const* d_in, const int* in_sizes, int n_in,
                              void* d_out, int out_size, void* d_ws, size_t ws_size,
                              hipStream_t stream) {
  const float* q    = (const float*)d_in[0];
  const float* k    = (const float*)d_in[1];
  const float* v    = (const float*)d_in[2];
  // d_in[3] gauge_weights: cancels in softmax, unused
  const float* Wcov = (const float*)d_in[4];
  const float* coup = (const float*)d_in[5];
  const float* W1   = (const float*)d_in[6];
  const float* b1   = (const float*)d_in[7];
  const float* W2   = (const float*)d_in[8];
  const float* b2   = (const float*)d_in[9];
  float* out = (float*)d_out;
  float* ws  = (float*)d_ws;
  float* ga   = ws;
  float* gb   = ws + 1*SD_;
  float* cm   = ws + 2*SD_;
  float* cq   = ws + 3*SD_;
  float* ck   = ws + 4*SD_;
  float* ckT  = ws + 5*SD_;
  float* E    = ws + 6*SD_;
  float* base = ws + 7*SD_;
  float* pq2 = base;        // 384
  float* Sga = base + 384;  float* Sgb = base + 768;
  float* Rcm = base + 1152; float* P2  = base + 1536;
  float* Cga = base + 1920; float* Cgb = base + 2304;
  float* Ccm = base + 2688;
  float* pE2 = base + 3072; // 96
  float* pen = base + 3168; // 96

  k1<<<dim3(576),  dim3(384), 0, stream>>>(q, k, Wcov, ga, gb, cm, pq2, cq, ck, ckT);
  k2<<<dim3(2880), dim3(384), 0, stream>>>(cq, ck, ckT, v, W1, b1, W2, E, pE2, pen,
                                           ga, gb, cm, Sga, Sgb, Rcm, P2, Cga, Cgb, Ccm,
                                           out + OUT_FS);
  k3<<<dim3(2305), dim3(384), 0, stream>>>(E, out + OUT_EV,
                                           pq2, Sga, Sgb, Rcm, P2, Cga, Cgb, Ccm,
                                           pE2, pen, coup, b2, out);
}